// Round 7
// baseline (151.855 us; speedup 1.0000x reference)
//
#include <hip/hip_runtime.h>

// Problem constants (fixed by reference)
constexpr int B = 4, T = 8, V = 256, F = 64;
constexpr int BT = B * T;            // 32 (b,t) slices
constexpr int CHUNK = 8;             // rows of i per block (proven sweet spot)
constexpr int NCHUNK = V / CHUNK;    // 32 -> grid = 32*32 = 1024 blocks (4 blocks/CU)
constexpr int NXCD = 8;
constexpr int K4 = F / 4;            // 16 float4 chunks per row

typedef float v2f __attribute__((ext_vector_type(2)));

// R12 — DIAGNOSTIC ROUND (intentional ~2x duration).
// The good kernel (~28us) has never produced a PMC row: it sits below the
// ~30 poison-fill dispatches (~40-48us) so it never enters the harness's
// top-5. This round runs the EXACT R10 kernel body TWICE per dispatch
// (opaque base pointer + opaque zero per pass prevent load/arith CSE;
// instruction mix identical, all counters exactly 2x) -> gl_fused ~56us
// lands in top-5 WITH its FETCH/WRITE/VALUBusy/Occupancy row.
// R13 reverts to single-pass and acts on the measured row.
//
// History: R6 packed-f32 math. R7 transpose copy: neutral. R8 occupancy
// force: destroyed load pipeline. R9/R11 LDS rowbuf: +10us — ds_read_b128
// is ~12cyc/instr on the one LDS pipe; 128/wave x 16 waves = ~10us/CU of
// pipe serialization. s_load path stays. R10 XCD swizzle: neutral, kept.
__global__ __launch_bounds__(256)
void gl_fused(const float* __restrict__ X, const float* __restrict__ A,
              float* __restrict__ OUT)
{
    const int tid = threadIdx.x;           // column j
    // XCD swizzle: consecutive logical blocks (same bt) pinned to one XCD
    const int lb  = (blockIdx.x & (NXCD - 1)) * (BT * NCHUNK / NXCD)
                  + (blockIdx.x >> 3);
    const int bt  = lb >> 5;               // / NCHUNK
    const int ic  = lb & (NCHUNK - 1);
    const int i0  = ic * CHUNK;

    __shared__ float wpart[4][CHUNK];      // per-wave partial row sums
    __shared__ float rden[CHUNK];          // reciprocal denominators

    // a -> uniform address, scalarized; keep as packed pairs
    v2f af2[F / 2];
#pragma unroll
    for (int k = 0; k < K4; ++k) {
        const float4 v = reinterpret_cast<const float4*>(A)[k];
        af2[2*k+0] = (v2f){v.x, v.y};
        af2[2*k+1] = (v2f){v.z, v.w};
    }

    const float* xbt0 = X + (size_t)bt * V * F;           // [256][64] tile

#pragma unroll 1
    for (int pass = 0; pass < 2; ++pass) {
        // Opaque per-pass state: compiler cannot CSE pass 2's loads or
        // arithmetic against pass 1 (base pointer and acc-seed are fresh).
        const float* xbt = xbt0;
        asm volatile("" : "+s"(xbt));      // opaque SGPR base (keeps s_load mix)
        float z = 0.0f;
        asm volatile("" : "+v"(z));        // opaque zero

        __syncthreads();                   // wpart/rden safe reuse across passes

        const float4* xrow4 = reinterpret_cast<const float4*>(xbt + (size_t)i0 * F);
        const float4* colp  = reinterpret_cast<const float4*>(xbt + (size_t)tid * F);

        v2f acc2[CHUNK];
#pragma unroll
        for (int r = 0; r < CHUNK; ++r) acc2[r] = (v2f){z, z};

#pragma unroll
        for (int k = 0; k < K4; ++k) {
            const float4 xv = colp[k];
            const v2f xlo = (v2f){xv.x, xv.y};
            const v2f xhi = (v2f){xv.z, xv.w};
#pragma unroll
            for (int r = 0; r < CHUNK; ++r) {
                const float4 sr = xrow4[r * K4 + k];    // uniform -> s_load_dwordx4
                const v2f d0 = xlo - (v2f){sr.x, sr.y}; // v_pk_add (neg mod)
                const v2f d1 = xhi - (v2f){sr.z, sr.w};
                const v2f a0 = __builtin_elementwise_max(d0, -d0);  // v_pk_max
                const v2f a1 = __builtin_elementwise_max(d1, -d1);
                acc2[r] = __builtin_elementwise_fma(a0, af2[2*k+0], acc2[r]);
                acc2[r] = __builtin_elementwise_fma(a1, af2[2*k+1], acc2[r]);
            }
        }

        float tmp[CHUNK];
#pragma unroll
        for (int r = 0; r < CHUNK; ++r) {
            const float s = acc2[r].x + acc2[r].y;
            tmp[r] = __expf(fmaxf(s, 0.0f));
        }

        // block reduction: row sum = denominator (symmetry)
        const int lane = tid & 63;
        const int wv   = tid >> 6;
#pragma unroll
        for (int r = 0; r < CHUNK; ++r) {
            float v = tmp[r];
            v += __shfl_xor(v, 32);
            v += __shfl_xor(v, 16);
            v += __shfl_xor(v, 8);
            v += __shfl_xor(v, 4);
            v += __shfl_xor(v, 2);
            v += __shfl_xor(v, 1);
            if (lane == 0) wpart[wv][r] = v;
        }
        __syncthreads();
        if (tid < CHUNK) {
            const float d = wpart[0][tid] + wpart[1][tid]
                          + wpart[2][tid] + wpart[3][tid];
            rden[tid] = 1.0f / d;
        }
        __syncthreads();

        // S[bt, i0+r, tid]; both passes store identical values (idempotent)
        float* obase = OUT + (((size_t)bt * V + i0) * V) + tid;
#pragma unroll
        for (int r = 0; r < CHUNK; ++r)
            obase[(size_t)r * V] = tmp[r] * rden[r];
    }
}

extern "C" void kernel_launch(void* const* d_in, const int* in_sizes, int n_in,
                              void* d_out, int out_size, void* d_ws, size_t ws_size,
                              hipStream_t stream)
{
    const float* X = (const float*)d_in[0];   // [B,T,V,F] fp32
    const float* A = (const float*)d_in[1];   // [F,1]     fp32
    float* OUT = (float*)d_out;               // [B,T,V,V] fp32

    dim3 grid(BT * NCHUNK), block(256);
    gl_fused<<<grid, block, 0, stream>>>(X, A, OUT);
}

// Round 8
// 74.260 us; speedup vs baseline: 2.0449x; 2.0449x over previous
//
#include <hip/hip_runtime.h>

// Problem constants (fixed by reference)
constexpr int B = 4, T = 8, V = 256, F = 64;
constexpr int BT = B * T;            // 32 (b,t) slices
constexpr int CHUNK = 4;             // R13: halved -> more blocks, fewer VGPRs
constexpr int NCHUNK = V / CHUNK;    // 64 -> grid = 32*64 = 2048 (8 blocks/CU)
constexpr int NXCD = 8;
constexpr int K4 = F / 4;            // 16 float4 chunks per row

typedef float v2f __attribute__((ext_vector_type(2)));

// Block = (bt, 4-row chunk). Thread tid owns column j=tid.
// score(i,j) symmetric -> denom[i] = row-i sum -> block-local reduction.
//
// R12 DIAGNOSTIC FINDINGS (first real gl_fused PMC rows):
//   FETCH = 2.26MB/pass = X exactly -> NO over-fetch (R8's 48.8MB was
//   VGPR=32 SPILL traffic, misread). WRITE ~= output -> no write-allocate
//   tax. hbm_gbps ~196 -> not BW-bound. 52us/pass @1 wave/SIMD vs 27us
//   @4 waves/SIMD -> latency-stall-bound and TLP-RESPONSIVE.
// R13: raise occupancy by cutting real VGPR demand (NOT by forcing the
//   bound — R8's spill disaster):
//   (a) CHUNK 8->4: acc2 16->8 VGPR, s_loads/wave 128->64, grid 2048.
//   (b) 'a' read in-loop from uniform addr: loop-invariant + uniform ->
//       compiler hoists into SGPRs (~64 SGPR, budget ok), freeing the 32
//       VGPRs af2 used to pin.
//   (c) #pragma unroll 4 on k-loop: col prefetch depth 4 float4 (16 VGPR
//       in flight) instead of the full-unroll 16 (64 VGPR).
//   Target VGPR <= 64 -> 7-8 waves/SIMD (2x current TLP).
// History: R6 packed math (kept). R7 transpose: neutral. R8 forced bound:
//   spills. R9/R11 LDS rowbuf: LDS-pipe serialization (~12cyc/ds_read_b128
//   x 128/wave). R10 XCD swizzle: neutral, kept (harmless).
__global__ __launch_bounds__(256)
void gl_fused(const float* __restrict__ X, const float* __restrict__ A,
              float* __restrict__ OUT)
{
    const int tid = threadIdx.x;           // column j
    // XCD swizzle: consecutive logical blocks (same bt) pinned to one XCD
    const int lb  = (blockIdx.x & (NXCD - 1)) * (BT * NCHUNK / NXCD)
                  + (blockIdx.x >> 3);
    const int bt  = lb >> 6;               // / NCHUNK (=64)
    const int ic  = lb & (NCHUNK - 1);
    const int i0  = ic * CHUNK;

    const float* xbt = X + (size_t)bt * V * F;            // [256][64] tile
    const float4* xrow4 = reinterpret_cast<const float4*>(xbt + (size_t)i0 * F);
    const float4* a4    = reinterpret_cast<const float4*>(A);

    __shared__ float wpart[4][CHUNK];      // per-wave partial row sums
    __shared__ float rden[CHUNK];          // reciprocal denominators

    v2f acc2[CHUNK];
#pragma unroll
    for (int r = 0; r < CHUNK; ++r) acc2[r] = (v2f){0.0f, 0.0f};

    // stream own column; a and rows from uniform addresses (SGPR-resident)
    const float4* colp = reinterpret_cast<const float4*>(xbt + (size_t)tid * F);
#pragma unroll 4
    for (int k = 0; k < K4; ++k) {
        const float4 xv = colp[k];
        const float4 av = a4[k];                    // uniform, loop-inv -> SGPRs
        const v2f xlo = (v2f){xv.x, xv.y};
        const v2f xhi = (v2f){xv.z, xv.w};
        const v2f alo = (v2f){av.x, av.y};
        const v2f ahi = (v2f){av.z, av.w};
#pragma unroll
        for (int r = 0; r < CHUNK; ++r) {
            const float4 sr = xrow4[r * K4 + k];    // uniform -> s_load_dwordx4
            const v2f d0 = xlo - (v2f){sr.x, sr.y}; // v_pk_add (neg mod)
            const v2f d1 = xhi - (v2f){sr.z, sr.w};
            const v2f a0 = __builtin_elementwise_max(d0, -d0);  // v_pk_max
            const v2f a1 = __builtin_elementwise_max(d1, -d1);
            acc2[r] = __builtin_elementwise_fma(a0, alo, acc2[r]); // v_pk_fma
            acc2[r] = __builtin_elementwise_fma(a1, ahi, acc2[r]);
        }
    }

    float tmp[CHUNK];
#pragma unroll
    for (int r = 0; r < CHUNK; ++r) {
        const float s = acc2[r].x + acc2[r].y;
        tmp[r] = __expf(fmaxf(s, 0.0f));
    }

    // block reduction: row sum = denominator (symmetry)
    const int lane = tid & 63;
    const int wv   = tid >> 6;
#pragma unroll
    for (int r = 0; r < CHUNK; ++r) {
        float v = tmp[r];
        v += __shfl_xor(v, 32);
        v += __shfl_xor(v, 16);
        v += __shfl_xor(v, 8);
        v += __shfl_xor(v, 4);
        v += __shfl_xor(v, 2);
        v += __shfl_xor(v, 1);
        if (lane == 0) wpart[wv][r] = v;
    }
    __syncthreads();
    if (tid < CHUNK) {
        const float d = wpart[0][tid] + wpart[1][tid] + wpart[2][tid] + wpart[3][tid];
        rden[tid] = 1.0f / d;
    }
    __syncthreads();

    // S[bt, i0+r, tid] = tmp[r] / denom[i0+r]; consecutive tids -> coalesced
    float* obase = OUT + (((size_t)bt * V + i0) * V) + tid;
#pragma unroll
    for (int r = 0; r < CHUNK; ++r)
        obase[(size_t)r * V] = tmp[r] * rden[r];
}

extern "C" void kernel_launch(void* const* d_in, const int* in_sizes, int n_in,
                              void* d_out, int out_size, void* d_ws, size_t ws_size,
                              hipStream_t stream)
{
    const float* X = (const float*)d_in[0];   // [B,T,V,F] fp32
    const float* A = (const float*)d_in[1];   // [F,1]     fp32
    float* OUT = (float*)d_out;               // [B,T,V,V] fp32

    dim3 grid(BT * NCHUNK), block(256);
    gl_fused<<<grid, block, 0, stream>>>(X, A, OUT);
}